// Round 6
// baseline (849.712 us; speedup 1.0000x reference)
//
#include <hip/hip_runtime.h>

#define LOG2E 1.4426950408889634f
#define LN2   0.6931471805599453f

constexpr int Hh = 32;
constexpr int Pp = 3;
constexpr int Bb = 4096;
constexpr int Tt = 2048;
constexpr int Kk = 128;

constexpr int WAVES   = 4;               // waves per block
constexpr int BPB     = 8;               // batch rows per block (2 per wave)
constexpr int THREADS = 256;
constexpr int CH      = 64;              // timesteps per LDS chunk

typedef float v2 __attribute__((ext_vector_type(2)));

__device__ __forceinline__ v2 bc2(float x) { v2 r; r.x = x; r.y = x; return r; }

// ---- 16-lane rotational butterfly partial-sum via DPP (bound_ctrl=true) ----
template<int CTRL>
__device__ __forceinline__ float rot_add16(float v) {
    int r = __builtin_amdgcn_update_dpp(0, __float_as_int(v), CTRL, 0xF, 0xF, true);
    return v + __int_as_float(r);
}
// sum over each 32-lane half; both halves hold every unit once -> full sum in all lanes
__device__ __forceinline__ float red32(float v) {
    v = rot_add16<0x121>(v);  // row_ror:1
    v = rot_add16<0x122>(v);  // row_ror:2
    v = rot_add16<0x124>(v);  // row_ror:4
    v = rot_add16<0x128>(v);  // row_ror:8
    v += __shfl_xor(v, 16, 64);
    return v;
}
__device__ __forceinline__ v2 red2(v2 v) { v.x = red32(v.x); v.y = red32(v.y); return v; }

// v: lanes 0-31 hold LO-quantity, lanes 32-63 hold HI-quantity.
// After swap (ISA: vdst lanes0-31 <-> vsrc lanes32-63):
//   a = {hi | hi} (hi broadcast), b = {lo | lo} (lo broadcast).
__device__ __forceinline__ void half_bcast(float v, float& lo_all, float& hi_all) {
    float a = v, b = v;
    asm("v_permlane32_swap_b32 %0, %1" : "+v"(a), "+v"(b));
    hi_all = a;
    lo_all = b;
}

__device__ __forceinline__ v2 rcp2(v2 d) {
    v2 r;
    r.x = __builtin_amdgcn_rcpf(d.x);
    r.y = __builtin_amdgcn_rcpf(d.y);
    return r;
}
__device__ __forceinline__ v2 exp2v(v2 g) {
    v2 r;
    r.x = __builtin_amdgcn_exp2f(g.x);
    r.y = __builtin_amdgcn_exp2f(g.y);
    return r;
}

__global__ void __launch_bounds__(THREADS, 2) lstm_scan_kernel(
    const float* __restrict__ X,
    const float* __restrict__ W_ih,
    const float* __restrict__ W_hh,
    const float* __restrict__ b_ih,
    const float* __restrict__ b_hh,
    const float* __restrict__ W_hr,
    float* __restrict__ h_out)
{
    // per wave: CH timesteps x 8 floats {x0A,x0B,x1A,x1B,x2A,x2B,pad,pad}
    __shared__ float xs[WAVES][CH][8];

    const int tid  = threadIdx.x;
    const int lane = tid & 63;
    const int wv   = tid >> 6;        // wave in block (0..3)
    const int j    = lane & 31;       // hidden unit
    const int half = lane >> 5;       // 0: gates {i,g} ; 1: gates {f,o}
    const int bglob = blockIdx.x * BPB;
    const int rA = bglob + 2 * wv;    // this wave's two batch rows
    const int rB = rA + 1;

    // preact scales fold the exp2 conversion: sigmoid -> -log2e, tanh -> -2log2e
    const float S1 = -LOG2E;
    const float S2 = -2.0f * LOG2E;

    const int g0 = (half ? Hh : 0) + j;            // i-row or f-row  (sigmoid)
    const int g1 = (half ? 3 * Hh : 2 * Hh) + j;   // g-row or o-row
    const float sc0 = S1;
    const float sc1 = half ? S1 : S2;

    v2 wih0[3], whh0[3], wih1[3], whh1[3];
    #pragma unroll
    for (int p = 0; p < 3; ++p) {
        wih0[p] = bc2(W_ih[g0*3+p] * sc0);
        whh0[p] = bc2(W_hh[g0*3+p] * sc0);
        wih1[p] = bc2(W_ih[g1*3+p] * sc1);
        whh1[p] = bc2(W_hh[g1*3+p] * sc1);
    }
    const v2 bias0 = bc2((b_ih[g0] + b_hh[g0]) * sc0);
    const v2 bias1 = bc2((b_ih[g1] + b_hh[g1]) * sc1);
    const v2 whr0v = bc2(W_hr[0*Hh + j]);
    const v2 whr1v = bc2(W_hr[1*Hh + j]);
    const v2 whr2v = bc2(W_hr[2*Hh + j]);

    const v2 one     = bc2(1.0f);
    const v2 two     = bc2(2.0f);
    const v2 neg_one = bc2(-1.0f);
    const v2 two_s2  = bc2(2.0f * S2);   // tgs = S2*tanh(g) = 2*S2*rg - S2
    const v2 neg_s2  = bc2(-S2);

    v2 h0 = bc2(0.f), h1 = bc2(0.f), h2 = bc2(0.f);  // projected hidden {rowA,rowB}
    v2 c = bc2(0.f);                                 // cell state, PRE-SCALED by S2

    for (int t0 = 0; t0 < Tt; t0 += CH) {
        __syncthreads();
        // stage 8 rows x CH x 3 inputs, interleaved {A,B} per wave region
        #pragma unroll
        for (int i = 0; i < (BPB * CH * Pp) / THREADS; ++i) {  // 6 iters
            const int idx = tid + i * THREADS;
            const int row = idx / (CH * Pp);     // 0..7
            const int rem = idx % (CH * Pp);
            const int t   = rem / 3, p = rem % 3;
            xs[row >> 1][t][p * 2 + (row & 1)] =
                X[((size_t)(bglob + row) * Tt + t0 + t) * Pp + p];
        }
        __syncthreads();

        #pragma unroll 4
        for (int tt = 0; tt < CH; ++tt) {
            const float4 xa = *(const float4*)&xs[wv][tt][0];   // x0A x0B x1A x1B
            const float2 xb = *(const float2*)&xs[wv][tt][4];   // x2A x2B
            v2 x0; x0.x = xa.x; x0.y = xa.y;
            v2 x1; x1.x = xa.z; x1.y = xa.w;
            v2 x2; x2.x = xb.x; x2.y = xb.y;

            v2 a0 = bias0, a1 = bias1;
            a0 = __builtin_elementwise_fma(x0, wih0[0], a0);
            a0 = __builtin_elementwise_fma(x1, wih0[1], a0);
            a0 = __builtin_elementwise_fma(x2, wih0[2], a0);
            a0 = __builtin_elementwise_fma(h0, whh0[0], a0);
            a0 = __builtin_elementwise_fma(h1, whh0[1], a0);
            a0 = __builtin_elementwise_fma(h2, whh0[2], a0);
            a1 = __builtin_elementwise_fma(x0, wih1[0], a1);
            a1 = __builtin_elementwise_fma(x1, wih1[1], a1);
            a1 = __builtin_elementwise_fma(x2, wih1[2], a1);
            a1 = __builtin_elementwise_fma(h0, whh1[0], a1);
            a1 = __builtin_elementwise_fma(h1, whh1[1], a1);
            a1 = __builtin_elementwise_fma(h2, whh1[2], a1);

            const v2 s0 = rcp2(exp2v(a0) + one);  // lanes<32: sigma_i ; >=32: sigma_f
            const v2 s1 = rcp2(exp2v(a1) + one);  // lanes<32: rg      ; >=32: sigma_o

            float siA, sfA, siB, sfB, rgA, soA, rgB, soB;
            half_bcast(s0.x, siA, sfA);
            half_bcast(s0.y, siB, sfB);
            half_bcast(s1.x, rgA, soA);
            half_bcast(s1.y, rgB, soB);
            v2 si; si.x = siA; si.y = siB;
            v2 sf; sf.x = sfA; sf.y = sfB;
            v2 rg; rg.x = rgA; rg.y = rgB;
            v2 so; so.x = soA; so.y = soB;

            const v2 tgs = __builtin_elementwise_fma(two_s2, rg, neg_s2); // S2*tanh(g)
            c = __builtin_elementwise_fma(sf, c, si * tgs);               // pre-scaled

            // tanh(c_real) = 2/(1+e^{-2 c_real}) - 1 ; c already = S2*c_real
            const v2 tc = __builtin_elementwise_fma(two, rcp2(exp2v(c) + one), neg_one);
            const v2 a2 = so * tc;

            h0 = red2(a2 * whr0v);
            h1 = red2(a2 * whr1v);
            h2 = red2(a2 * whr2v);
        }
    }

    if (lane == 0) {
        h_out[rA*3+0] = h0.x; h_out[rA*3+1] = h1.x; h_out[rA*3+2] = h2.x;
        h_out[rB*3+0] = h0.y; h_out[rB*3+1] = h1.y; h_out[rB*3+2] = h2.y;
    }
}

__global__ void __launch_bounds__(256) score_loss_kernel(
    const float* __restrict__ x5,
    const float* __restrict__ h_ws,
    float* __restrict__ partial)
{
    const int gid = blockIdx.x * 256 + threadIdx.x;
    const int b = gid >> 7;
    const int k = gid & 127;
    const float h0 = h_ws[b*3+0];
    const float h1 = h_ws[b*3+1];
    const float h2 = h_ws[b*3+2];
    const float* xb = x5 + (size_t)b * (Pp * Kk);
    const float s = fmaf(h2, xb[2*Kk + k], fmaf(h1, xb[Kk + k], h0 * xb[k]));

    // -log_sigmoid(s) = softplus(-s), stable form
    const float z  = -s;
    const float az = fabsf(z);
    const float e  = __builtin_amdgcn_exp2f(-az * LOG2E);
    float l = fmaxf(z, 0.f) + __builtin_amdgcn_logf(1.f + e) * LN2;

    #pragma unroll
    for (int m = 1; m < 64; m <<= 1) l += __shfl_xor(l, m, 64);
    __shared__ float wsum[4];
    if ((threadIdx.x & 63) == 0) wsum[threadIdx.x >> 6] = l;
    __syncthreads();
    if (threadIdx.x == 0)
        partial[blockIdx.x] = wsum[0] + wsum[1] + wsum[2] + wsum[3];
}

__global__ void __launch_bounds__(256) final_reduce_kernel(
    const float* __restrict__ partial, float* __restrict__ out)
{
    float s = 0.f;
    for (int i = threadIdx.x; i < (Bb * Kk) / 256; i += 256) s += partial[i];
    #pragma unroll
    for (int m = 1; m < 64; m <<= 1) s += __shfl_xor(s, m, 64);
    __shared__ float wsum[4];
    if ((threadIdx.x & 63) == 0) wsum[threadIdx.x >> 6] = s;
    __syncthreads();
    if (threadIdx.x == 0)
        out[0] = (wsum[0] + wsum[1] + wsum[2] + wsum[3]) * (1.0f / (float)(Bb * Kk));
}

extern "C" void kernel_launch(void* const* d_in, const int* in_sizes, int n_in,
                              void* d_out, int out_size, void* d_ws, size_t ws_size,
                              hipStream_t stream)
{
    const float* X    = (const float*)d_in[0];
    const float* x5   = (const float*)d_in[1];
    const float* W_ih = (const float*)d_in[2];
    const float* W_hh = (const float*)d_in[3];
    const float* b_ih = (const float*)d_in[4];
    const float* b_hh = (const float*)d_in[5];
    const float* W_hr = (const float*)d_in[6];
    float* out = (float*)d_out;

    float* h_ws    = (float*)d_ws;            // 4096*3 floats
    float* partial = (float*)d_ws + Bb * Pp;  // 2048 floats

    hipLaunchKernelGGL(lstm_scan_kernel, dim3(Bb / BPB), dim3(THREADS), 0, stream,
                       X, W_ih, W_hh, b_ih, b_hh, W_hr, h_ws);
    hipLaunchKernelGGL(score_loss_kernel, dim3((Bb * Kk) / 256), dim3(256), 0, stream,
                       x5, h_ws, partial);
    hipLaunchKernelGGL(final_reduce_kernel, dim3(1), dim3(256), 0, stream,
                       partial, out);
}

// Round 7
// 592.571 us; speedup vs baseline: 1.4339x; 1.4339x over previous
//
#include <hip/hip_runtime.h>

#define LOG2E 1.4426950408889634f
#define LN2   0.6931471805599453f

constexpr int Hh = 32;
constexpr int Pp = 3;
constexpr int Bb = 4096;
constexpr int Tt = 2048;
constexpr int Kk = 128;

constexpr int BPB     = 8;               // batch rows per block (2 per wave)
constexpr int THREADS = 256;             // 4 waves
constexpr int CH      = 64;              // timesteps per LDS chunk

typedef float v2 __attribute__((ext_vector_type(2)));

__device__ __forceinline__ v2 bc2(float x) { v2 r; r.x = x; r.y = x; return r; }

// ---- 16-lane rotational butterfly partial sums via DPP (bound_ctrl=true) ----
template<int CTRL>
__device__ __forceinline__ float rot_add16(float v) {
    int r = __builtin_amdgcn_update_dpp(0, __float_as_int(v), CTRL, 0xF, 0xF, true);
    return v + __int_as_float(r);
}
// Full 32-lane row sum for rows mapped to lanes {b..b+15} U {b+32..b+47}.
// 4 DPP stages within each 16-group, then one permlane32 swap (i <-> i+32)
// pairs the two groups of the SAME row. All-VALU; validated in R3 (exact).
__device__ __forceinline__ float row_sum32(float v) {
    v = rot_add16<0x121>(v);  // row_ror:1
    v = rot_add16<0x122>(v);  // row_ror:2
    v = rot_add16<0x124>(v);  // row_ror:4
    v = rot_add16<0x128>(v);  // row_ror:8
    float a = v, b = v;
    asm("v_permlane32_swap_b32 %0, %1" : "+v"(a), "+v"(b));
    return a + b;
}

__device__ __forceinline__ float exp2a(float x) { return __builtin_amdgcn_exp2f(x); }
__device__ __forceinline__ float rcpa(float x)  { return __builtin_amdgcn_rcpf(x); }
__device__ __forceinline__ v2 exp2v(v2 g) {
    v2 r; r.x = exp2a(g.x); r.y = exp2a(g.y); return r;
}

__global__ void __launch_bounds__(THREADS, 2) lstm_scan_kernel(
    const float* __restrict__ X,
    const float* __restrict__ W_ih,
    const float* __restrict__ W_hh,
    const float* __restrict__ b_ih,
    const float* __restrict__ b_hh,
    const float* __restrict__ W_hr,
    float* __restrict__ h_out)
{
    __shared__ float xs[BPB][CH][4];

    const int tid  = threadIdx.x;
    const int lane = tid & 63;
    const int wv   = tid >> 6;                        // wave in block (0..3)
    // row = (lane>>4)&1 ; unit j = (lane&15) + 16*(lane>>5)
    const int rw   = (lane >> 4) & 1;                 // row within wave (0/1)
    const int j    = (lane & 15) + ((lane >> 5) << 4);// hidden unit 0..31
    const int rowg = wv * 2 + rw;                     // row within block (0..7)
    const int bglob = blockIdx.x * BPB;

    // v2 packs gate-pairs: qIF = {i,f}, qGO = {g,o}; preact scales fold exp2:
    // sigmoid rows -> -log2e ; tanh(g) row -> -2log2e
    const float S1 = -LOG2E;
    const float S2 = -2.0f * LOG2E;

    v2 wihIF[3], whhIF[3], wihGO[3], whhGO[3];
    #pragma unroll
    for (int p = 0; p < 3; ++p) {
        wihIF[p].x = W_ih[(0*Hh + j)*3 + p] * S1;
        wihIF[p].y = W_ih[(1*Hh + j)*3 + p] * S1;
        whhIF[p].x = W_hh[(0*Hh + j)*3 + p] * S1;
        whhIF[p].y = W_hh[(1*Hh + j)*3 + p] * S1;
        wihGO[p].x = W_ih[(2*Hh + j)*3 + p] * S2;
        wihGO[p].y = W_ih[(3*Hh + j)*3 + p] * S1;
        whhGO[p].x = W_hh[(2*Hh + j)*3 + p] * S2;
        whhGO[p].y = W_hh[(3*Hh + j)*3 + p] * S1;
    }
    v2 biasIF, biasGO;
    biasIF.x = (b_ih[0*Hh + j] + b_hh[0*Hh + j]) * S1;
    biasIF.y = (b_ih[1*Hh + j] + b_hh[1*Hh + j]) * S1;
    biasGO.x = (b_ih[2*Hh + j] + b_hh[2*Hh + j]) * S2;
    biasGO.y = (b_ih[3*Hh + j] + b_hh[3*Hh + j]) * S1;
    const float whr0 = W_hr[0*Hh + j];
    const float whr1 = W_hr[1*Hh + j];
    const float whr2 = W_hr[2*Hh + j];

    const v2 one = bc2(1.0f);
    const float two_s2 = 2.0f * S2;   // S2*tanh(g) = 2*S2*rg - S2
    const float neg_s2 = -S2;

    float h0 = 0.f, h1 = 0.f, h2 = 0.f;  // projected hidden (real scale)
    float c  = 0.f;                      // cell state, PRE-SCALED by S2

    for (int t0 = 0; t0 < Tt; t0 += CH) {
        __syncthreads();
        // stage X[b, t0:t0+CH, :3] -> xs[row][t][p] (slot 3 = pad)
        #pragma unroll
        for (int i = 0; i < (BPB * CH * Pp) / THREADS; ++i) {  // 6 iters
            const int idx = tid + i * THREADS;
            const int row = idx / (CH * Pp);     // 0..7
            const int rem = idx % (CH * Pp);
            const int t   = rem / 3, p = rem % 3;
            xs[row][t][p] = X[((size_t)(bglob + row) * Tt + t0 + t) * Pp + p];
        }
        __syncthreads();

        #pragma unroll 4
        for (int tt = 0; tt < CH; ++tt) {
            const float4 xv = *(const float4*)&xs[rowg][tt][0];

            v2 aIF = biasIF, aGO = biasGO;
            aIF = __builtin_elementwise_fma(bc2(xv.x), wihIF[0], aIF);
            aIF = __builtin_elementwise_fma(bc2(xv.y), wihIF[1], aIF);
            aIF = __builtin_elementwise_fma(bc2(xv.z), wihIF[2], aIF);
            aIF = __builtin_elementwise_fma(bc2(h0),   whhIF[0], aIF);
            aIF = __builtin_elementwise_fma(bc2(h1),   whhIF[1], aIF);
            aIF = __builtin_elementwise_fma(bc2(h2),   whhIF[2], aIF);
            aGO = __builtin_elementwise_fma(bc2(xv.x), wihGO[0], aGO);
            aGO = __builtin_elementwise_fma(bc2(xv.y), wihGO[1], aGO);
            aGO = __builtin_elementwise_fma(bc2(xv.z), wihGO[2], aGO);
            aGO = __builtin_elementwise_fma(bc2(h0),   whhGO[0], aGO);
            aGO = __builtin_elementwise_fma(bc2(h1),   whhGO[1], aGO);
            aGO = __builtin_elementwise_fma(bc2(h2),   whhGO[2], aGO);

            const v2 qIF = exp2v(aIF) + one;   // {1+e^-i, 1+e^-f}
            const v2 qGO = exp2v(aGO) + one;   // {1+e^-2g, 1+e^-o}

            // shared rcp, all in-lane: R = 1/(qi qf qg qo)
            const float m01 = qIF.x * qIF.y;
            const float m23 = qGO.x * qGO.y;
            const float R   = rcpa(m01 * m23);
            const float rIF = R * m23;             // 1/(qi qf)
            const float rGO = R * m01;             // 1/(qg qo)
            const float si  = rIF * qIF.y;         // sigmoid(i)
            const float sf  = rIF * qIF.x;         // sigmoid(f)
            const float rg  = rGO * qGO.y;         // 1/(1+e^-2g)
            const float so  = rGO * qGO.x;         // sigmoid(o)

            const float tgs = fmaf(two_s2, rg, neg_s2);  // S2*tanh(g)
            c = fmaf(sf, c, si * tgs);                   // pre-scaled cell

            // tanh(c_real) = 2/(1+e^{-2 c_real}) - 1 ; c = S2*c_real
            const float tc = fmaf(2.f, rcpa(1.0f + exp2a(c)), -1.f);
            const float a2 = so * tc;

            h0 = row_sum32(a2 * whr0);
            h1 = row_sum32(a2 * whr1);
            h2 = row_sum32(a2 * whr2);
        }
    }

    // lanes 0 (row A) and 16 (row B) hold the full sums
    if ((lane & 15) == 0 && lane < 32) {
        const int b = bglob + rowg;
        h_out[b*3+0] = h0;
        h_out[b*3+1] = h1;
        h_out[b*3+2] = h2;
    }
}

__global__ void __launch_bounds__(256) score_loss_kernel(
    const float* __restrict__ x5,
    const float* __restrict__ h_ws,
    float* __restrict__ partial)
{
    const int gid = blockIdx.x * 256 + threadIdx.x;
    const int b = gid >> 7;
    const int k = gid & 127;
    const float h0 = h_ws[b*3+0];
    const float h1 = h_ws[b*3+1];
    const float h2 = h_ws[b*3+2];
    const float* xb = x5 + (size_t)b * (Pp * Kk);
    const float s = fmaf(h2, xb[2*Kk + k], fmaf(h1, xb[Kk + k], h0 * xb[k]));

    // -log_sigmoid(s) = softplus(-s), stable form
    const float z  = -s;
    const float az = fabsf(z);
    const float e  = __builtin_amdgcn_exp2f(-az * LOG2E);
    float l = fmaxf(z, 0.f) + __builtin_amdgcn_logf(1.f + e) * LN2;

    #pragma unroll
    for (int m = 1; m < 64; m <<= 1) l += __shfl_xor(l, m, 64);
    __shared__ float wsum[4];
    if ((threadIdx.x & 63) == 0) wsum[threadIdx.x >> 6] = l;
    __syncthreads();
    if (threadIdx.x == 0)
        partial[blockIdx.x] = wsum[0] + wsum[1] + wsum[2] + wsum[3];
}

__global__ void __launch_bounds__(256) final_reduce_kernel(
    const float* __restrict__ partial, float* __restrict__ out)
{
    float s = 0.f;
    for (int i = threadIdx.x; i < (Bb * Kk) / 256; i += 256) s += partial[i];
    #pragma unroll
    for (int m = 1; m < 64; m <<= 1) s += __shfl_xor(s, m, 64);
    __shared__ float wsum[4];
    if ((threadIdx.x & 63) == 0) wsum[threadIdx.x >> 6] = s;
    __syncthreads();
    if (threadIdx.x == 0)
        out[0] = (wsum[0] + wsum[1] + wsum[2] + wsum[3]) * (1.0f / (float)(Bb * Kk));
}

extern "C" void kernel_launch(void* const* d_in, const int* in_sizes, int n_in,
                              void* d_out, int out_size, void* d_ws, size_t ws_size,
                              hipStream_t stream)
{
    const float* X    = (const float*)d_in[0];
    const float* x5   = (const float*)d_in[1];
    const float* W_ih = (const float*)d_in[2];
    const float* W_hh = (const float*)d_in[3];
    const float* b_ih = (const float*)d_in[4];
    const float* b_hh = (const float*)d_in[5];
    const float* W_hr = (const float*)d_in[6];
    float* out = (float*)d_out;

    float* h_ws    = (float*)d_ws;            // 4096*3 floats
    float* partial = (float*)d_ws + Bb * Pp;  // 2048 floats

    hipLaunchKernelGGL(lstm_scan_kernel, dim3(Bb / BPB), dim3(THREADS), 0, stream,
                       X, W_ih, W_hh, b_ih, b_hh, W_hr, h_ws);
    hipLaunchKernelGGL(score_loss_kernel, dim3((Bb * Kk) / 256), dim3(256), 0, stream,
                       x5, h_ws, partial);
    hipLaunchKernelGGL(final_reduce_kernel, dim3(1), dim3(256), 0, stream,
                       partial, out);
}

// Round 8
// 577.600 us; speedup vs baseline: 1.4711x; 1.0259x over previous
//
#include <hip/hip_runtime.h>

#define LOG2E 1.4426950408889634f
#define LN2   0.6931471805599453f

constexpr int Hh = 32;
constexpr int Pp = 3;
constexpr int Bb = 4096;
constexpr int Tt = 2048;
constexpr int Kk = 128;

constexpr int BPB     = 8;               // batch rows per block (2 per wave)
constexpr int THREADS = 256;             // 4 waves
constexpr int CH      = 64;              // timesteps per LDS chunk
constexpr int XP      = CH * 4 + 4;      // 260 floats: stride%32=4 -> rows on disjoint bank quads

typedef float v2 __attribute__((ext_vector_type(2)));

__device__ __forceinline__ v2 bc2(float x) { v2 r; r.x = x; r.y = x; return r; }

// ---- 16-lane rotational butterfly partial sums via DPP (bound_ctrl=true) ----
template<int CTRL>
__device__ __forceinline__ float rot_add16(float v) {
    int r = __builtin_amdgcn_update_dpp(0, __float_as_int(v), CTRL, 0xF, 0xF, true);
    return v + __int_as_float(r);
}
// Full 32-lane row sum for rows mapped to lanes {b..b+15} U {b+32..b+47}.
// 4 DPP stages within each 16-group, then one permlane32 swap (i <-> i+32)
// pairs the two groups of the SAME row. All-VALU; validated in R3/R7 (exact).
__device__ __forceinline__ float row_sum32(float v) {
    v = rot_add16<0x121>(v);  // row_ror:1
    v = rot_add16<0x122>(v);  // row_ror:2
    v = rot_add16<0x124>(v);  // row_ror:4
    v = rot_add16<0x128>(v);  // row_ror:8
    float a = v, b = v;
    asm("v_permlane32_swap_b32 %0, %1" : "+v"(a), "+v"(b));
    return a + b;
}

__device__ __forceinline__ float exp2a(float x) { return __builtin_amdgcn_exp2f(x); }
__device__ __forceinline__ float rcpa(float x)  { return __builtin_amdgcn_rcpf(x); }
__device__ __forceinline__ v2 exp2v(v2 g) {
    v2 r; r.x = exp2a(g.x); r.y = exp2a(g.y); return r;
}

__global__ void __launch_bounds__(THREADS, 2) lstm_scan_kernel(
    const float* __restrict__ X,
    const float* __restrict__ W_ih,
    const float* __restrict__ W_hh,
    const float* __restrict__ b_ih,
    const float* __restrict__ b_hh,
    const float* __restrict__ W_hr,
    float* __restrict__ h_out)
{
    __shared__ float xs[BPB * XP];

    const int tid  = threadIdx.x;
    const int lane = tid & 63;
    const int wv   = tid >> 6;                        // wave in block (0..3)
    const int rw   = (lane >> 4) & 1;                 // row within wave (0/1)
    const int j    = (lane & 15) + ((lane >> 5) << 4);// hidden unit 0..31
    const int rowg = wv * 2 + rw;                     // row within block (0..7)
    const int bglob = blockIdx.x * BPB;
    const float* __restrict__ xrow = xs + rowg * XP;  // this lane's row slab

    // v2 packs gate-pairs: qIF = {i,f}, qGO = {g,o}; preact scales fold exp2:
    // sigmoid rows -> -log2e ; tanh(g) row -> -2log2e
    const float S1 = -LOG2E;
    const float S2 = -2.0f * LOG2E;

    v2 wihIF[3], whhIF[3], wihGO[3], whhGO[3];
    #pragma unroll
    for (int p = 0; p < 3; ++p) {
        wihIF[p].x = W_ih[(0*Hh + j)*3 + p] * S1;
        wihIF[p].y = W_ih[(1*Hh + j)*3 + p] * S1;
        whhIF[p].x = W_hh[(0*Hh + j)*3 + p] * S1;
        whhIF[p].y = W_hh[(1*Hh + j)*3 + p] * S1;
        wihGO[p].x = W_ih[(2*Hh + j)*3 + p] * S2;
        wihGO[p].y = W_ih[(3*Hh + j)*3 + p] * S1;
        whhGO[p].x = W_hh[(2*Hh + j)*3 + p] * S2;
        whhGO[p].y = W_hh[(3*Hh + j)*3 + p] * S1;
    }
    v2 biasIF, biasGO;
    biasIF.x = (b_ih[0*Hh + j] + b_hh[0*Hh + j]) * S1;
    biasIF.y = (b_ih[1*Hh + j] + b_hh[1*Hh + j]) * S1;
    biasGO.x = (b_ih[2*Hh + j] + b_hh[2*Hh + j]) * S2;
    biasGO.y = (b_ih[3*Hh + j] + b_hh[3*Hh + j]) * S1;
    const float whr0 = W_hr[0*Hh + j];
    const float whr1 = W_hr[1*Hh + j];
    const float whr2 = W_hr[2*Hh + j];

    const v2 one = bc2(1.0f);
    const float two_s2 = 2.0f * S2;   // S2*tanh(g) = 2*S2*rg - S2
    const float neg_s2 = -S2;

    float h0 = 0.f, h1 = 0.f, h2 = 0.f;  // projected hidden (real scale)
    float c  = 0.f;                      // cell state, PRE-SCALED by S2

    for (int t0 = 0; t0 < Tt; t0 += CH) {
        __syncthreads();
        // stage X[b, t0:t0+CH, :3] -> xs[row*XP + t*4 + p] (slot 3 = pad)
        #pragma unroll
        for (int i = 0; i < (BPB * CH * Pp) / THREADS; ++i) {  // 6 iters
            const int idx = tid + i * THREADS;
            const int row = idx / (CH * Pp);     // 0..7
            const int rem = idx % (CH * Pp);
            const int t   = rem / 3, p = rem % 3;
            xs[row * XP + t * 4 + p] =
                X[((size_t)(bglob + row) * Tt + t0 + t) * Pp + p];
        }
        __syncthreads();

        #pragma unroll 4
        for (int tt = 0; tt < CH; ++tt) {
            const float4 xv = *(const float4*)(xrow + tt * 4);

            v2 aIF = biasIF, aGO = biasGO;
            aIF = __builtin_elementwise_fma(bc2(xv.x), wihIF[0], aIF);
            aIF = __builtin_elementwise_fma(bc2(xv.y), wihIF[1], aIF);
            aIF = __builtin_elementwise_fma(bc2(xv.z), wihIF[2], aIF);
            aIF = __builtin_elementwise_fma(bc2(h0),   whhIF[0], aIF);
            aIF = __builtin_elementwise_fma(bc2(h1),   whhIF[1], aIF);
            aIF = __builtin_elementwise_fma(bc2(h2),   whhIF[2], aIF);
            aGO = __builtin_elementwise_fma(bc2(xv.x), wihGO[0], aGO);
            aGO = __builtin_elementwise_fma(bc2(xv.y), wihGO[1], aGO);
            aGO = __builtin_elementwise_fma(bc2(xv.z), wihGO[2], aGO);
            aGO = __builtin_elementwise_fma(bc2(h0),   whhGO[0], aGO);
            aGO = __builtin_elementwise_fma(bc2(h1),   whhGO[1], aGO);
            aGO = __builtin_elementwise_fma(bc2(h2),   whhGO[2], aGO);

            const v2 qIF = exp2v(aIF) + one;   // {1+e^-i, 1+e^-f}
            const v2 qGO = exp2v(aGO) + one;   // {1+e^-2g, 1+e^-o}

            // shared rcp, all in-lane: R = 1/(qi qf qg qo)
            const float m01 = qIF.x * qIF.y;
            const float m23 = qGO.x * qGO.y;
            const float R   = rcpa(m01 * m23);
            const float rIF = R * m23;             // 1/(qi qf)
            const float rGO = R * m01;             // 1/(qg qo)
            const float si  = rIF * qIF.y;         // sigmoid(i)
            const float sf  = rIF * qIF.x;         // sigmoid(f)
            const float rg  = rGO * qGO.y;         // 1/(1+e^-2g)
            const float so  = rGO * qGO.x;         // sigmoid(o)

            const float tgs = fmaf(two_s2, rg, neg_s2);  // S2*tanh(g)
            c = fmaf(sf, c, si * tgs);                   // pre-scaled cell

            // tanh(c_real) = 2/(1+e^{-2 c_real}) - 1 ; c = S2*c_real
            const float tc = fmaf(2.f, rcpa(1.0f + exp2a(c)), -1.f);
            const float a2 = so * tc;

            h0 = row_sum32(a2 * whr0);
            h1 = row_sum32(a2 * whr1);
            h2 = row_sum32(a2 * whr2);
        }
    }

    // lanes 0 (row A) and 16 (row B) hold the full sums
    if ((lane & 15) == 0 && lane < 32) {
        const int b = bglob + rowg;
        h_out[b*3+0] = h0;
        h_out[b*3+1] = h1;
        h_out[b*3+2] = h2;
    }
}

__global__ void __launch_bounds__(256) score_loss_kernel(
    const float* __restrict__ x5,
    const float* __restrict__ h_ws,
    float* __restrict__ partial)
{
    const int gid = blockIdx.x * 256 + threadIdx.x;
    const int b = gid >> 7;
    const int k = gid & 127;
    const float h0 = h_ws[b*3+0];
    const float h1 = h_ws[b*3+1];
    const float h2 = h_ws[b*3+2];
    const float* xb = x5 + (size_t)b * (Pp * Kk);
    const float s = fmaf(h2, xb[2*Kk + k], fmaf(h1, xb[Kk + k], h0 * xb[k]));

    // -log_sigmoid(s) = softplus(-s), stable form
    const float z  = -s;
    const float az = fabsf(z);
    const float e  = __builtin_amdgcn_exp2f(-az * LOG2E);
    float l = fmaxf(z, 0.f) + __builtin_amdgcn_logf(1.f + e) * LN2;

    #pragma unroll
    for (int m = 1; m < 64; m <<= 1) l += __shfl_xor(l, m, 64);
    __shared__ float wsum[4];
    if ((threadIdx.x & 63) == 0) wsum[threadIdx.x >> 6] = l;
    __syncthreads();
    if (threadIdx.x == 0)
        partial[blockIdx.x] = wsum[0] + wsum[1] + wsum[2] + wsum[3];
}

__global__ void __launch_bounds__(256) final_reduce_kernel(
    const float* __restrict__ partial, float* __restrict__ out)
{
    float s = 0.f;
    for (int i = threadIdx.x; i < (Bb * Kk) / 256; i += 256) s += partial[i];
    #pragma unroll
    for (int m = 1; m < 64; m <<= 1) s += __shfl_xor(s, m, 64);
    __shared__ float wsum[4];
    if ((threadIdx.x & 63) == 0) wsum[threadIdx.x >> 6] = s;
    __syncthreads();
    if (threadIdx.x == 0)
        out[0] = (wsum[0] + wsum[1] + wsum[2] + wsum[3]) * (1.0f / (float)(Bb * Kk));
}

extern "C" void kernel_launch(void* const* d_in, const int* in_sizes, int n_in,
                              void* d_out, int out_size, void* d_ws, size_t ws_size,
                              hipStream_t stream)
{
    const float* X    = (const float*)d_in[0];
    const float* x5   = (const float*)d_in[1];
    const float* W_ih = (const float*)d_in[2];
    const float* W_hh = (const float*)d_in[3];
    const float* b_ih = (const float*)d_in[4];
    const float* b_hh = (const float*)d_in[5];
    const float* W_hr = (const float*)d_in[6];
    float* out = (float*)d_out;

    float* h_ws    = (float*)d_ws;            // 4096*3 floats
    float* partial = (float*)d_ws + Bb * Pp;  // 2048 floats

    hipLaunchKernelGGL(lstm_scan_kernel, dim3(Bb / BPB), dim3(THREADS), 0, stream,
                       X, W_ih, W_hh, b_ih, b_hh, W_hr, h_ws);
    hipLaunchKernelGGL(score_loss_kernel, dim3((Bb * Kk) / 256), dim3(256), 0, stream,
                       x5, h_ws, partial);
    hipLaunchKernelGGL(final_reduce_kernel, dim3(1), dim3(256), 0, stream,
                       partial, out);
}